// Round 5
// baseline (308.203 us; speedup 1.0000x reference)
//
#include <hip/hip_runtime.h>

// GCN 2-layer, N=100000, E=1600000, dim 64, fp32 in/out.
// CSR build via two-level bucket sort (cache-local), then per layer:
// gemm64 (fp32 in, bf16 out, rows pre-scaled by dinv[row]) +
// gather_nodes: one wave per node, 4 edge-slots x 16 lanes, pure
// unpack-add inner loop, dinv[dst] factored out (wave-uniform).

#define THREADS 256
#define BSHIFT 10            // bucket = dst >> 10  (1024 nodes per bucket)
#define NBUCK_MAX 128        // K = ceil(100000/1024) = 98
#define CHUNK 2048

__device__ __forceinline__ unsigned int f2bf(float f) {   // RNE fp32->bf16
    unsigned int u = __float_as_uint(f);
    return (u + 0x7fffu + ((u >> 16) & 1u)) >> 16;
}
__device__ __forceinline__ float bfl(unsigned int u) { return __uint_as_float(u << 16); }
__device__ __forceinline__ float bfh(unsigned int u) { return __uint_as_float(u & 0xffff0000u); }

// ---- coarse bucket histogram (LDS-staged) ----
__global__ __launch_bounds__(256) void bucket_hist(const int* __restrict__ dst,
                                                   int* __restrict__ bcnt,
                                                   int e, int K) {
    __shared__ int h[NBUCK_MAX];
    int t = threadIdx.x;
    if (t < NBUCK_MAX) h[t] = 0;
    __syncthreads();
    int stride = gridDim.x * blockDim.x;
    for (int i = blockIdx.x * blockDim.x + t; i < e; i += stride)
        atomicAdd(&h[dst[i] >> BSHIFT], 1);
    __syncthreads();
    if (t < K && h[t] > 0) atomicAdd(&bcnt[t], h[t]);
}

// ---- exclusive scan of K bucket counts (single block) ----
__global__ __launch_bounds__(128) void bucket_scan(const int* __restrict__ bcnt,
                                                   int* __restrict__ boffs,
                                                   int* __restrict__ bcur,
                                                   int* __restrict__ rowptr_last,
                                                   int K, int e) {
    __shared__ int ts[NBUCK_MAX];
    int t = threadIdx.x;
    int v = (t < K) ? bcnt[t] : 0;
    ts[t] = v;
    __syncthreads();
    for (int off = 1; off < NBUCK_MAX; off <<= 1) {
        int u = (t >= off) ? ts[t - off] : 0;
        __syncthreads();
        ts[t] += u;
        __syncthreads();
    }
    if (t < K) { int ex = ts[t] - v; boffs[t] = ex; bcur[t] = ex; }
    if (t == 0) { boffs[K] = e; *rowptr_last = e; }
}

// ---- partition edges into bucket-contiguous packed pairs ----
__global__ __launch_bounds__(256) void bucket_partition(const int* __restrict__ src,
                                                        const int* __restrict__ dst,
                                                        int* __restrict__ bcur,
                                                        unsigned int* __restrict__ pairs,
                                                        int e) {
    __shared__ int cnt[NBUCK_MAX], offs[NBUCK_MAX], cur[NBUCK_MAX], base[NBUCK_MAX];
    __shared__ unsigned int sP[CHUNK];
    __shared__ unsigned char sB[CHUNK];
    const int t = threadIdx.x;
    const int cb = blockIdx.x * CHUNK;
    if (t < NBUCK_MAX) cnt[t] = 0;
    __syncthreads();

    unsigned int ep[8]; int eb[8];
#pragma unroll
    for (int j = 0; j < 8; j++) {
        int idx = cb + j * 256 + t;
        eb[j] = -1;
        if (idx < e) {
            int s = src[idx], d = dst[idx];
            ep[j] = ((unsigned int)s << BSHIFT) | (unsigned int)(d & ((1 << BSHIFT) - 1));
            eb[j] = d >> BSHIFT;
            atomicAdd(&cnt[eb[j]], 1);
        }
    }
    __syncthreads();
    if (t < NBUCK_MAX) offs[t] = cnt[t];
    __syncthreads();
    for (int off = 1; off < NBUCK_MAX; off <<= 1) {
        int u = 0;
        if (t < NBUCK_MAX && t >= off) u = offs[t - off];
        __syncthreads();
        if (t < NBUCK_MAX) offs[t] += u;
        __syncthreads();
    }
    if (t < NBUCK_MAX) {
        int ex = offs[t] - cnt[t];
        offs[t] = ex;
        cur[t] = ex;
        if (cnt[t] > 0) base[t] = atomicAdd(&bcur[t], cnt[t]);
    }
    __syncthreads();
#pragma unroll
    for (int j = 0; j < 8; j++) {
        if (eb[j] >= 0) {
            int pos = atomicAdd(&cur[eb[j]], 1);
            sP[pos] = ep[j];
            sB[pos] = (unsigned char)eb[j];
        }
    }
    __syncthreads();
    int nv = min(CHUNK, e - cb);
    for (int i = t; i < nv; i += 256) {
        int b = sB[i];
        pairs[base[b] + (i - offs[b])] = sP[i];
    }
}

// ---- per-bucket counting sort -> final CSR + rowptr + dinv ----
__global__ __launch_bounds__(256) void bucket_csr(const unsigned int* __restrict__ pairs,
                                                  const int* __restrict__ boffs,
                                                  int* __restrict__ rowptr,
                                                  float* __restrict__ dinv,
                                                  int* __restrict__ srcs,
                                                  int n) {
    __shared__ int cnt[1024];
    __shared__ int cur[1024];
    __shared__ int tsum[256];
    const int b = blockIdx.x;
    const int t = threadIdx.x;
    const int nb = b << BSHIFT;
    const int nn = min(1024, n - nb);
    const int s = boffs[b], eEnd = boffs[b + 1];
    const unsigned int DM = (1u << BSHIFT) - 1u;

#pragma unroll
    for (int j = 0; j < 4; j++) cnt[t * 4 + j] = 0;
    __syncthreads();
    for (int i = s + t; i < eEnd; i += 256)
        atomicAdd(&cnt[pairs[i] & DM], 1);
    __syncthreads();
    int c0 = cnt[t * 4], c1 = cnt[t * 4 + 1], c2 = cnt[t * 4 + 2], c3 = cnt[t * 4 + 3];
    int sum = c0 + c1 + c2 + c3;
    tsum[t] = sum;
    __syncthreads();
    for (int off = 1; off < 256; off <<= 1) {
        int u = (t >= off) ? tsum[t - off] : 0;
        __syncthreads();
        tsum[t] += u;
        __syncthreads();
    }
    int ex = tsum[t] - sum;
    int o0 = ex, o1 = ex + c0, o2 = o1 + c1, o3 = o2 + c2;
    cur[t * 4] = o0; cur[t * 4 + 1] = o1; cur[t * 4 + 2] = o2; cur[t * 4 + 3] = o3;
    int k = t * 4;
    if (k < nn) {
        *(int4*)(rowptr + nb + k) = make_int4(s + o0, s + o1, s + o2, s + o3);
        *(float4*)(dinv + nb + k) = make_float4(rsqrtf((float)c0 + 1.f),
                                                rsqrtf((float)c1 + 1.f),
                                                rsqrtf((float)c2 + 1.f),
                                                rsqrtf((float)c3 + 1.f));
    }
    __syncthreads();
    for (int i = s + t; i < eEnd; i += 256) {
        unsigned int p = pairs[i];
        int pos = atomicAdd(&cur[p & DM], 1);
        srcs[s + pos] = (int)(p >> BSHIFT);
    }
}

// ---- Y16[N,64](bf16) = (X[N,64] @ W[64,64]) * dinv[row] ----
__global__ __launch_bounds__(256) void gemm64(const float* __restrict__ X,
                                              const float* __restrict__ W,
                                              const float* __restrict__ dinv,
                                              unsigned short* __restrict__ Y16,
                                              int nrows) {
    __shared__ float Wl[64 * 64];
    __shared__ float Xl[64 * 65];
    const int tid = threadIdx.x;
    const long rowBase = (long)blockIdx.x * 64;

    for (int i = tid; i < 1024; i += 256)
        ((float4*)Wl)[i] = ((const float4*)W)[i];

    for (int i = tid; i < 1024; i += 256) {
        int r = i >> 4, c4 = i & 15;
        long row = rowBase + r;
        float4 v = make_float4(0.f, 0.f, 0.f, 0.f);
        if (row < nrows) v = ((const float4*)(X + row * 64))[c4];
        int bo = r * 65 + c4 * 4;
        Xl[bo + 0] = v.x; Xl[bo + 1] = v.y; Xl[bo + 2] = v.z; Xl[bo + 3] = v.w;
    }
    __syncthreads();

    const int r = tid & 63;
    const int cg = tid >> 6;
    float acc[16];
#pragma unroll
    for (int j = 0; j < 16; j++) acc[j] = 0.f;

#pragma unroll 8
    for (int kk = 0; kk < 64; kk++) {
        float xv = Xl[r * 65 + kk];
        const float* wr = Wl + kk * 64 + cg * 16;
#pragma unroll
        for (int j = 0; j < 16; j++) acc[j] += xv * wr[j];
    }

    long row = rowBase + r;
    if (row < nrows) {
        float di = dinv[row];
        unsigned int p[8];
#pragma unroll
        for (int j = 0; j < 8; j++)
            p[j] = f2bf(acc[2 * j] * di) | (f2bf(acc[2 * j + 1] * di) << 16);
        uint4* yo = (uint4*)(Y16 + row * 64 + cg * 16);
        yo[0] = make_uint4(p[0], p[1], p[2], p[3]);
        yo[1] = make_uint4(p[4], p[5], p[6], p[7]);
    }
}

// ---- gather: one wave per node, 4 edge-slots x 16 lanes ----
// XW rows are bf16, pre-scaled by dinv[src]. Inner loop: pure unpack+add.
// out[node] = relu( (sum_edges row'[s] + row'[node]) * dinv[node] + bias ).
__global__ __launch_bounds__(256) void gather_nodes(const unsigned short* __restrict__ XW,
                                                    const int* __restrict__ rowptr,
                                                    const int* __restrict__ srcs,
                                                    const float* __restrict__ dinv,
                                                    const float* __restrict__ bias,
                                                    float* __restrict__ out, int n) {
    int node = (blockIdx.x * 256 + threadIdx.x) >> 6;
    if (node >= n) return;
    int lane = threadIdx.x & 63;
    int slot = lane >> 4;          // 0..3 edge slot
    int fl   = lane & 15;          // feature quad: 4*fl .. 4*fl+3
    const uint2* Xp = (const uint2*)XW;   // [N][16], each uint2 = 4 bf16
    int beg = rowptr[node], end = rowptr[node + 1];
    float di = dinv[node];

    float a0 = 0.f, a1 = 0.f, a2 = 0.f, a3 = 0.f;
    if (slot == 0) {               // self-loop folded in before reduction
        uint2 sv = Xp[(size_t)node * 16 + fl];
        a0 = bfl(sv.x); a1 = bfh(sv.x); a2 = bfl(sv.y); a3 = bfh(sv.y);
    }
#pragma unroll 2
    for (int e = beg + slot; e < end; e += 4) {
        int s = srcs[e];
        uint2 v = Xp[(size_t)s * 16 + fl];
        a0 += bfl(v.x); a1 += bfh(v.x); a2 += bfl(v.y); a3 += bfh(v.y);
    }
    // combine the 4 slots (butterfly over lane bits 4,5)
    a0 += __shfl_xor(a0, 16); a0 += __shfl_xor(a0, 32);
    a1 += __shfl_xor(a1, 16); a1 += __shfl_xor(a1, 32);
    a2 += __shfl_xor(a2, 16); a2 += __shfl_xor(a2, 32);
    a3 += __shfl_xor(a3, 16); a3 += __shfl_xor(a3, 32);

    if (slot == 0) {
        float4 bv = ((const float4*)bias)[fl];
        float4 o;
        o.x = fmaxf(a0 * di + bv.x, 0.f);
        o.y = fmaxf(a1 * di + bv.y, 0.f);
        o.z = fmaxf(a2 * di + bv.z, 0.f);
        o.w = fmaxf(a3 * di + bv.w, 0.f);
        ((float4*)(out + (size_t)node * 64))[fl] = o;
    }
}

extern "C" void kernel_launch(void* const* d_in, const int* in_sizes, int n_in,
                              void* d_out, int out_size, void* d_ws, size_t ws_size,
                              hipStream_t stream) {
    const float* x  = (const float*)d_in[0];
    const int*   ei = (const int*)d_in[1];
    const float* W1 = (const float*)d_in[2];
    const float* b1 = (const float*)d_in[3];
    const float* W2 = (const float*)d_in[4];
    const float* b2 = (const float*)d_in[5];
    float* out = (float*)d_out;

    const int N = in_sizes[0] / 64;
    const int E = in_sizes[1] / 2;
    const int* srcA = ei;
    const int* dstA = ei + E;
    const int K = (N + (1 << BSHIFT) - 1) >> BSHIFT;   // 98

    char* ws = (char*)d_ws;
    auto alloc = [&](size_t bytes) { char* p = ws; ws += (bytes + 255) & ~(size_t)255; return p; };
    unsigned short* A16 = (unsigned short*)alloc((size_t)N * 64 * 2);  // XW' bf16 (also pairs)
    float* B      = (float*)alloc((size_t)N * 64 * 4);                 // h1 fp32
    float* dinv   = (float*)alloc((size_t)N * 4);
    int*   rowptr = (int*)  alloc((size_t)(N + 1) * 4);
    int*   srcs_sorted = (int*)alloc((size_t)E * 4);
    int*   bcnt   = (int*)  alloc(NBUCK_MAX * 4);
    int*   boffs  = (int*)  alloc((NBUCK_MAX + 1) * 4);
    int*   bcur   = (int*)  alloc(NBUCK_MAX * 4);
    unsigned int* pairs = (unsigned int*)A16;   // 6.4MB, dead before gemm writes A16

    // ---- CSR build ----
    hipMemsetAsync(bcnt, 0, NBUCK_MAX * 4, stream);
    bucket_hist     <<<256, 256, 0, stream>>>(dstA, bcnt, E, K);
    bucket_scan     <<<1, 128, 0, stream>>>(bcnt, boffs, bcur, rowptr + N, K, E);
    bucket_partition<<<(E + CHUNK - 1) / CHUNK, 256, 0, stream>>>(srcA, dstA, bcur, pairs, E);
    bucket_csr      <<<K, 256, 0, stream>>>(pairs, boffs, rowptr, dinv, srcs_sorted, N);

    const int gemmBlocks = (N + 63) / 64;
    const int nodeBlocks = (N + 3) / 4;   // 4 waves/block, 1 node/wave

    // ---- layer 1 ----
    gemm64      <<<gemmBlocks, 256, 0, stream>>>(x, W1, dinv, A16, N);
    gather_nodes<<<nodeBlocks, 256, 0, stream>>>(A16, rowptr, srcs_sorted, dinv, b1, B, N);

    // ---- layer 2 ----
    gemm64      <<<gemmBlocks, 256, 0, stream>>>(B, W2, dinv, A16, N);
    gather_nodes<<<nodeBlocks, 256, 0, stream>>>(A16, rowptr, srcs_sorted, dinv, b2, out, N);
}